// Round 1
// baseline (187.562 us; speedup 1.0000x reference)
//
#include <hip/hip_runtime.h>

// Problem constants (from reference setup_inputs)
#define BB 32
#define SS 4
#define KK 11
#define CC 9
#define HH 128
#define WW 128
#define HWSZ (HH * WW)   // 16384

// Kernel 1: one block per (b,s,k). Fused heatmap-MSE partial sum + argmax.
// combined_hm_preds: [B,S,K,HW], heatmaps: [B,K,HW]
__global__ __launch_bounds__(256) void k1_scan(
    const float* __restrict__ hm_preds,
    const float* __restrict__ heatmaps,
    float* __restrict__ ws_sum,   // [B*S*K] partial MSE
    int*   __restrict__ ws_idx,   // [B*S*K] argmax index
    float* __restrict__ ws_max)   // [B*S*K] max value (== conf)
{
    const int blk = blockIdx.x;          // linear (b,s,k) — matches hm_preds tile order
    const int k   = blk % KK;
    const int bs  = blk / KK;            // b*S + s
    const int b   = bs / SS;

    const float4* __restrict__ pred = (const float4*)(hm_preds + (size_t)blk * HWSZ);
    const float4* __restrict__ gt   = (const float4*)(heatmaps + (size_t)(b * KK + k) * HWSZ);

    const int tid = threadIdx.x;
    float sum  = 0.0f;
    float bmax = -INFINITY;
    int   bidx = 0;

    // 16384 floats = 4096 float4 = 16 iterations of 256 threads
    #pragma unroll
    for (int i = 0; i < HWSZ / 4 / 256; ++i) {
        const int v4 = i * 256 + tid;
        const float4 p = pred[v4];
        const float4 g = gt[v4];
        const float d0 = p.x - g.x, d1 = p.y - g.y, d2 = p.z - g.z, d3 = p.w - g.w;
        sum += d0 * d0 + d1 * d1 + d2 * d2 + d3 * d3;
        const int base = v4 * 4;
        // strict > keeps the FIRST occurrence within this thread (indices increase)
        if (p.x > bmax) { bmax = p.x; bidx = base; }
        if (p.y > bmax) { bmax = p.y; bidx = base + 1; }
        if (p.z > bmax) { bmax = p.z; bidx = base + 2; }
        if (p.w > bmax) { bmax = p.w; bidx = base + 3; }
    }

    // wave64 shuffle reduction: sum + (max, lowest-index tie-break)
    #pragma unroll
    for (int off = 32; off > 0; off >>= 1) {
        sum += __shfl_down(sum, off);
        const float ov = __shfl_down(bmax, off);
        const int   oi = __shfl_down(bidx, off);
        if (ov > bmax || (ov == bmax && oi < bidx)) { bmax = ov; bidx = oi; }
    }

    __shared__ float s_sum[4];
    __shared__ float s_max[4];
    __shared__ int   s_idx[4];
    const int wave = tid >> 6;
    if ((tid & 63) == 0) { s_sum[wave] = sum; s_max[wave] = bmax; s_idx[wave] = bidx; }
    __syncthreads();
    if (tid == 0) {
        #pragma unroll
        for (int wv = 1; wv < 4; ++wv) {
            sum += s_sum[wv];
            if (s_max[wv] > bmax || (s_max[wv] == bmax && s_idx[wv] < bidx)) {
                bmax = s_max[wv]; bidx = s_idx[wv];
            }
        }
        ws_sum[blk] = sum;
        ws_idx[blk] = bidx;
        ws_max[blk] = bmax;
    }
}

// Kernel 2: one wave (64 threads) per (b,s). Lanes 0..10 each finish one k:
// gather 9 class preds at argmax pos, xy/conf loss, validity mask.
// combined_lb_preds: [B,S,9,HW], labels: [B,K,11]
__global__ __launch_bounds__(64) void k2_finish(
    const float* __restrict__ lb_preds,
    const float* __restrict__ labels,
    const float* __restrict__ ws_sum,
    const int*   __restrict__ ws_idx,
    const float* __restrict__ ws_max,
    float* __restrict__ out)   // [2 * B*S]: hm_loss then lb_loss
{
    const int bs   = blockIdx.x;    // b*S + s
    const int b    = bs / SS;
    const int lane = threadIdx.x;

    float part = 0.0f;
    float lk   = 0.0f;
    if (lane < KK) {
        const int g = bs * KK + lane;
        part = ws_sum[g];
        const int   idx  = ws_idx[g];
        const float conf = ws_max[g];
        const float* __restrict__ lab = labels + (size_t)(b * KK + lane) * 11;
        const float gx = lab[9];
        const float gy = lab[10];
        const bool valid = (gx >= 0.0f) && (gy >= 0.0f) &&
                           (gx < (float)HH) && (gy < (float)WW);
        // ref: m = H; x = idx // m, y = idx % m; pos = x*W + y == idx (H==W)
        const float x = (float)(idx / HH);
        const float y = (float)(idx % HH);
        const float dx = gx - x, dy = gy - y;
        const float xy_loss   = dx * dx + dy * dy;
        const float cf        = 1.0f - conf;
        const float conf_loss = cf * cf;
        float cls = 0.0f;
        const float* __restrict__ lp = lb_preds + (size_t)bs * CC * HWSZ + idx;
        #pragma unroll
        for (int c = 0; c < CC; ++c) {
            const float d = lp[(size_t)c * HWSZ] - lab[c];
            cls += d * d;
        }
        lk = valid ? (cls + xy_loss + conf_loss) : 0.0f;
    }

    #pragma unroll
    for (int off = 32; off > 0; off >>= 1) {
        part += __shfl_down(part, off);
        lk   += __shfl_down(lk, off);
    }
    if (lane == 0) {
        out[bs]           = part;   // hm_loss [B,S] row-major
        out[BB * SS + bs] = lk;     // lb_loss [B,S]
    }
}

extern "C" void kernel_launch(void* const* d_in, const int* in_sizes, int n_in,
                              void* d_out, int out_size, void* d_ws, size_t ws_size,
                              hipStream_t stream) {
    const float* hm_preds = (const float*)d_in[0];   // [32,4,11,128,128]
    const float* lb_preds = (const float*)d_in[1];   // [32,4,9,128,128]
    const float* heatmaps = (const float*)d_in[2];   // [32,11,128,128]
    const float* labels   = (const float*)d_in[3];   // [32,11,11]
    float* out = (float*)d_out;                      // 256 floats

    const int NT = BB * SS * KK;                     // 1408
    float* ws_sum = (float*)d_ws;
    int*   ws_idx = (int*)(ws_sum + NT);
    float* ws_max = (float*)(ws_idx + NT);

    k1_scan<<<NT, 256, 0, stream>>>(hm_preds, heatmaps, ws_sum, ws_idx, ws_max);
    k2_finish<<<BB * SS, 64, 0, stream>>>(lb_preds, labels, ws_sum, ws_idx, ws_max, out);
}

// Round 3
// 181.332 us; speedup vs baseline: 1.0344x; 1.0344x over previous
//
#include <hip/hip_runtime.h>

// Problem constants (from reference setup_inputs)
#define BB 32
#define SS 4
#define KK 11
#define CC 9
#define HH 128
#define WW 128
#define HWSZ (HH * WW)       // 16384
#define NC 4                 // HW chunks per (b,k)
#define CHUNK (HWSZ / NC)    // 4096 floats = 1024 float4 = 4 iters x 256 thr

// native vector type — __builtin_nontemporal_load requires scalar/native-vector
typedef float vfloat4 __attribute__((ext_vector_type(4)));

// Kernel 1: one block per (b, k, chunk). Loads the gt chunk ONCE and streams
// all S=4 pred stacks against it: fused MSE partial + per-chunk argmax.
// hm_preds: [B,S,K,HW], heatmaps: [B,K,HW]
// ws layout: [(b*K + k)*S + s]*NC + c
__global__ __launch_bounds__(256) void k1_scan(
    const float* __restrict__ hm_preds,
    const float* __restrict__ heatmaps,
    float* __restrict__ ws_sum,
    int*   __restrict__ ws_idx,
    float* __restrict__ ws_max)
{
    const int blk = blockIdx.x;          // (b*KK + k)*NC + c
    const int c   = blk % NC;
    const int bk  = blk / NC;            // b*KK + k
    const int b   = bk / KK;
    const int k   = bk % KK;

    const vfloat4* __restrict__ gt =
        (const vfloat4*)(heatmaps + (size_t)bk * HWSZ + (size_t)c * CHUNK);
    // pred base for s=0; stride between stacks is KK*HWSZ floats
    const float* __restrict__ pred0 =
        hm_preds + ((size_t)(b * SS) * KK + k) * HWSZ + (size_t)c * CHUNK;

    const int tid = threadIdx.x;
    float sum[SS]  = {0.f, 0.f, 0.f, 0.f};
    float bmax[SS] = {-INFINITY, -INFINITY, -INFINITY, -INFINITY};
    int   bidx[SS] = {0, 0, 0, 0};

    const int gbase0 = c * CHUNK;        // global flat base of this chunk

    #pragma unroll
    for (int i = 0; i < CHUNK / 4 / 256; ++i) {   // 4 iterations
        const int v4 = i * 256 + tid;
        const vfloat4 g = __builtin_nontemporal_load(&gt[v4]);
        const int base = gbase0 + v4 * 4;
        #pragma unroll
        for (int s = 0; s < SS; ++s) {
            const vfloat4 p = __builtin_nontemporal_load(
                (const vfloat4*)(pred0 + (size_t)s * (KK * HWSZ)) + v4);
            const float d0 = p.x - g.x, d1 = p.y - g.y;
            const float d2 = p.z - g.z, d3 = p.w - g.w;
            sum[s] += d0 * d0 + d1 * d1 + d2 * d2 + d3 * d3;
            // strict > keeps FIRST occurrence (indices increase within thread)
            if (p.x > bmax[s]) { bmax[s] = p.x; bidx[s] = base; }
            if (p.y > bmax[s]) { bmax[s] = p.y; bidx[s] = base + 1; }
            if (p.z > bmax[s]) { bmax[s] = p.z; bidx[s] = base + 2; }
            if (p.w > bmax[s]) { bmax[s] = p.w; bidx[s] = base + 3; }
        }
    }

    // wave64 shuffle reduction per stack: sum + (max, lowest-index tie-break)
    #pragma unroll
    for (int off = 32; off > 0; off >>= 1) {
        #pragma unroll
        for (int s = 0; s < SS; ++s) {
            sum[s] += __shfl_down(sum[s], off);
            const float ov = __shfl_down(bmax[s], off);
            const int   oi = __shfl_down(bidx[s], off);
            if (ov > bmax[s] || (ov == bmax[s] && oi < bidx[s])) {
                bmax[s] = ov; bidx[s] = oi;
            }
        }
    }

    __shared__ float s_sum[SS][4];
    __shared__ float s_max[SS][4];
    __shared__ int   s_idx[SS][4];
    const int wave = tid >> 6;
    if ((tid & 63) == 0) {
        #pragma unroll
        for (int s = 0; s < SS; ++s) {
            s_sum[s][wave] = sum[s]; s_max[s][wave] = bmax[s]; s_idx[s][wave] = bidx[s];
        }
    }
    __syncthreads();
    if (tid == 0) {
        #pragma unroll
        for (int s = 0; s < SS; ++s) {
            float fs = s_sum[s][0], fm = s_max[s][0];
            int   fi = s_idx[s][0];
            #pragma unroll
            for (int wv = 1; wv < 4; ++wv) {
                fs += s_sum[s][wv];
                if (s_max[s][wv] > fm || (s_max[s][wv] == fm && s_idx[s][wv] < fi)) {
                    fm = s_max[s][wv]; fi = s_idx[s][wv];
                }
            }
            const int g = (bk * SS + s) * NC + c;
            ws_sum[g] = fs;
            ws_idx[g] = fi;
            ws_max[g] = fm;
        }
    }
}

// Kernel 2: one wave per (b,s). Lane k<11 combines the 4 chunk partials
// (ascending chunk order preserves the first-max tie-break since chunk
// indices are globally increasing), then the label loss.
// lb_preds: [B,S,9,HW], labels: [B,K,11]
__global__ __launch_bounds__(64) void k2_finish(
    const float* __restrict__ lb_preds,
    const float* __restrict__ labels,
    const float* __restrict__ ws_sum,
    const int*   __restrict__ ws_idx,
    const float* __restrict__ ws_max,
    float* __restrict__ out)   // [2 * B*S]: hm_loss then lb_loss
{
    const int bs   = blockIdx.x;    // b*S + s
    const int b    = bs / SS;
    const int s    = bs % SS;
    const int lane = threadIdx.x;

    float part = 0.0f;
    float lk   = 0.0f;
    if (lane < KK) {
        const int g0 = ((b * KK + lane) * SS + s) * NC;
        float sum  = 0.0f;
        float conf = -INFINITY;
        int   idx  = 0x7fffffff;
        #pragma unroll
        for (int c = 0; c < NC; ++c) {
            sum += ws_sum[g0 + c];
            const float v  = ws_max[g0 + c];
            const int   ix = ws_idx[g0 + c];
            if (v > conf || (v == conf && ix < idx)) { conf = v; idx = ix; }
        }
        part = sum;

        const float* __restrict__ lab = labels + (size_t)(b * KK + lane) * 11;
        const float gx = lab[9];
        const float gy = lab[10];
        const bool valid = (gx >= 0.0f) && (gy >= 0.0f) &&
                           (gx < (float)HH) && (gy < (float)WW);
        // ref: m = H; x = idx // m, y = idx % m; pos = x*W + y == idx (H==W)
        const float x = (float)(idx / HH);
        const float y = (float)(idx % HH);
        const float dx = gx - x, dy = gy - y;
        const float xy_loss   = dx * dx + dy * dy;
        const float cf        = 1.0f - conf;
        const float conf_loss = cf * cf;
        float cls = 0.0f;
        const float* __restrict__ lp = lb_preds + (size_t)bs * CC * HWSZ + idx;
        #pragma unroll
        for (int c = 0; c < CC; ++c) {
            const float d = lp[(size_t)c * HWSZ] - lab[c];
            cls += d * d;
        }
        lk = valid ? (cls + xy_loss + conf_loss) : 0.0f;
    }

    #pragma unroll
    for (int off = 32; off > 0; off >>= 1) {
        part += __shfl_down(part, off);
        lk   += __shfl_down(lk, off);
    }
    if (lane == 0) {
        out[bs]           = part;   // hm_loss [B,S]
        out[BB * SS + bs] = lk;     // lb_loss [B,S]
    }
}

extern "C" void kernel_launch(void* const* d_in, const int* in_sizes, int n_in,
                              void* d_out, int out_size, void* d_ws, size_t ws_size,
                              hipStream_t stream) {
    const float* hm_preds = (const float*)d_in[0];   // [32,4,11,128,128]
    const float* lb_preds = (const float*)d_in[1];   // [32,4,9,128,128]
    const float* heatmaps = (const float*)d_in[2];   // [32,11,128,128]
    const float* labels   = (const float*)d_in[3];   // [32,11,11]
    float* out = (float*)d_out;                      // 256 floats

    const int NP = BB * KK * SS * NC;                // 5632 partials
    float* ws_sum = (float*)d_ws;
    int*   ws_idx = (int*)(ws_sum + NP);
    float* ws_max = (float*)(ws_idx + NP);

    k1_scan<<<BB * KK * NC, 256, 0, stream>>>(hm_preds, heatmaps, ws_sum, ws_idx, ws_max);
    k2_finish<<<BB * SS, 64, 0, stream>>>(lb_preds, labels, ws_sum, ws_idx, ws_max, out);
}